// Round 3
// baseline (805.025 us; speedup 1.0000x reference)
//
#include <hip/hip_runtime.h>
#include <hip/hip_bf16.h>

// ---------------- problem constants ----------------
#define TPAD   65656    // t_padded
#define TOUT   65536
#define CCH    384      // channels
#define NROWS  768      // SIZE * C
#define HOP    392
#define NB     168
#define BS     512      // fft block size
#define KPAD   416      // 392 padded to multiple of 32
#define M1     129024   // NROWS * NB
#define M2     131072   // 2 * TOUT
#define NT1    13       // KPAD/32 K-steps in gemm1

typedef __attribute__((ext_vector_type(8))) _Float16 f16x8;
typedef __attribute__((ext_vector_type(4))) _Float16 f16x4;
typedef __attribute__((ext_vector_type(2))) _Float16 f16x2;
typedef __attribute__((ext_vector_type(4))) float    f32x4;
typedef __attribute__((ext_vector_type(8))) float    f32x8;

__device__ __forceinline__ void gload_lds16(const void* g, void* l) {
    __builtin_amdgcn_global_load_lds(
        (__attribute__((address_space(1))) void*)g,
        (__attribute__((address_space(3))) void*)l, 16, 0, 0);
}

// ---------------- h = irfft_backward(kernel_fft, 512) ----------------
__global__ void build_h_kernel(const float* __restrict__ kfft, float* __restrict__ h) {
    __shared__ float Ks[257];
    int j = threadIdx.x;          // 0..511
    if (j < 257) Ks[j] = kfft[j];
    __syncthreads();
    float acc = Ks[0] + ((j & 1) ? -Ks[256] : Ks[256]);
    const float w0 = 6.2831853071795864769f / 512.0f;
    for (int f = 1; f < 256; ++f) {
        int m = (f * j) & 511;            // exact integer phase reduction
        acc += 2.0f * Ks[f] * cosf(w0 * (float)m);
    }
    h[j] = acc * (1.0f / 512.0f);
}

// ---------------- Ht[j][i] = h[(j-i) mod 512], i<392 else 0 ----------------
__global__ void build_ht_kernel(const float* __restrict__ h, _Float16* __restrict__ Ht) {
    int j = blockIdx.x;                               // 0..511
    int i = blockIdx.y * 256 + threadIdx.x;           // 0..511
    if (i >= KPAD) return;
    float v = (i < HOP) ? h[(j - i) & 511] : 0.0f;
    Ht[j * KPAD + i] = (_Float16)v;
}

// ---------------- spT[d][c] = std[c] * vt[c][d] ----------------
__global__ void build_spt_kernel(const float* __restrict__ sstd, const float* __restrict__ vt,
                                 _Float16* __restrict__ spT) {
    int d = blockIdx.x;      // 0..383
    int c = threadIdx.x;     // 0..383
    spT[d * CCH + c] = (_Float16)(sstd[c] * vt[c * CCH + d]);
}

// ---------------- stage 1: stationary-B, barrier-free K-loop ----------------
// yb[rb][perm(j)] = sum_i noise16[rb][i] * Ht[j][i]
// Tile 128m x 64n. The block's full B slice (64 rows x 416 K = 53KB) is staged
// into LDS ONCE (one barrier). The K-loop then has NO barriers: A fragments are
// loaded straight from noise (each lane's frag = contiguous 32B f32 chunk of one
// row), converted to f16 in-register, depth-1 prefetched under the MFMAs.
__global__ __launch_bounds__(256) void gemm1_kernel(const float* __restrict__ noise,
                                                    const _Float16* __restrict__ Ht,
                                                    _Float16* __restrict__ yb) {
    __shared__ __align__(16) _Float16 Bs[NT1 * 64 * 32];   // 53,248 B -> 3 blocks/CU
    const int tid  = threadIdx.x;
    const int lane = tid & 63;
    const int w    = tid >> 6;
    const int quad = lane >> 4, lm = lane & 15;
    const int wm   = w >> 1, wn = w & 1;

    // 8064 blocks; bijective XCD-chunked remap, 1008 lids per XCD.
    // Consecutive lids on one XCD share the same m-panel (8 n-blocks) -> A in L2.
    const int bid = blockIdx.x;
    const int lid = (bid & 7) * 1008 + (bid >> 3);
    const int n0  = (lid & 7) * 64;
    const int m0  = (lid >> 3) * 128;

    // ---- stage all NT1 B K-tiles into LDS (linear dest per global_load_lds) ----
    {
        int row = tid >> 2, col = (tid & 3) * 8;
        const _Float16* src = Ht + (n0 + row) * KPAD + col;
        _Float16* dst = &Bs[0] + (tid & ~63) * 8;
#pragma unroll
        for (int kt = 0; kt < NT1; ++kt)
            gload_lds16(src + kt * 32, dst + kt * 2048);
    }

    // ---- per-lane A row pointers (4 m-frags, row = m0 + wm*64 + mi*16 + lm) ----
    const float* asrc[4]; int alim[4];
#pragma unroll
    for (int mi = 0; mi < 4; ++mi) {
        int m = m0 + wm * 64 + mi * 16 + lm;
        int r = m / NB, b = m - r * NB;
        asrc[mi] = noise + (size_t)r * TPAD + b * HOP;
        alim[mi] = (b == NB - 1) ? (TPAD - (NB - 1) * HOP) : HOP;   // 192 or 392
    }

    f32x4 pv[4][2];
    // limits are multiples of 8, i0 multiple of 8 -> whole 8-seg valid or zero
#define LOADA(K0) {                                                        \
        int i0 = (K0) + quad * 8;                                          \
        _Pragma("unroll")                                                  \
        for (int mi = 0; mi < 4; ++mi) {                                   \
            if (i0 < alim[mi]) {                                           \
                pv[mi][0] = *(const f32x4*)(asrc[mi] + i0);                \
                pv[mi][1] = *(const f32x4*)(asrc[mi] + i0 + 4);            \
            } else { pv[mi][0] = (f32x4){}; pv[mi][1] = (f32x4){}; }       \
        }                                                                  \
    }

    LOADA(0);
    __syncthreads();          // Bs resident; prologue A loads drained too

    f32x4 acc[4][2] = {};

    for (int kt = 0; kt < NT1; ++kt) {
        f16x8 a[4];
#pragma unroll
        for (int mi = 0; mi < 4; ++mi) {
            f32x8 v = {pv[mi][0].x, pv[mi][0].y, pv[mi][0].z, pv[mi][0].w,
                       pv[mi][1].x, pv[mi][1].y, pv[mi][1].z, pv[mi][1].w};
            a[mi] = __builtin_convertvector(v, f16x8);
        }
        if (kt + 1 < NT1) LOADA((kt + 1) * 32);   // async, lands next iteration

        f16x8 b[2];
#pragma unroll
        for (int ni = 0; ni < 2; ++ni)
            b[ni] = *(const f16x8*)(&Bs[0] + kt * 2048 +
                                    (wn * 32 + ni * 16 + lm) * 32 + quad * 8);
#pragma unroll
        for (int mi = 0; mi < 4; ++mi)
#pragma unroll
            for (int ni = 0; ni < 2; ++ni)
                acc[mi][ni] = __builtin_amdgcn_mfma_f32_16x16x32_f16(a[mi], b[ni], acc[mi][ni], 0, 0, 0);
    }
#undef LOADA

    // epilogue: lane lm holds logical cols {ni*16+lm, ni=0,1} of its 32-col group;
    // store them contiguously at stored col lm*2+ni -> one 4B f16x2 store per (mi,e).
#pragma unroll
    for (int mi = 0; mi < 4; ++mi)
#pragma unroll
        for (int e = 0; e < 4; ++e) {
            int row = m0 + wm * 64 + mi * 16 + quad * 4 + e;
            f16x2 o = {(_Float16)acc[mi][0][e], (_Float16)acc[mi][1][e]};
            *(f16x2*)(yb + (size_t)row * BS + n0 + wn * 32 + lm * 2) = o;
        }
}

// stored col for logical col j (within each 32-col group: lm*2+ni <- ni*16+lm)
__device__ __forceinline__ int permcol(int j) {
    return (j & ~31) | ((j & 15) << 1) | ((j >> 4) & 1);
}

// ---------------- overlap-add + transpose: Yt[n][t][c] ----------------
__global__ __launch_bounds__(256) void oa_kernel(const _Float16* __restrict__ yb,
                                                 _Float16* __restrict__ Yt) {
    __shared__ float Ls[32][33];
    const int tx = threadIdx.x & 31, ty = threadIdx.x >> 5;   // 32 x 8
    const int t0 = blockIdx.x * 32, c0 = blockIdx.y * 32, n = blockIdx.z;
#pragma unroll
    for (int s = 0; s < 4; ++s) {
        int cc = ty + s * 8;
        int r  = n * CCH + c0 + cc;
        int g  = t0 + tx + 120;
        int b  = g / HOP;
        int j  = g - b * HOP;
        size_t base = (size_t)(r * NB + b) * BS;
        float v = (float)yb[base + permcol(j)];
        if (j < 120) v += (float)yb[base - BS + permcol(j + 392)];  // yb[r, b-1, j+392]
        Ls[cc][tx] = v;
    }
    __syncthreads();
#pragma unroll
    for (int s = 0; s < 4; ++s) {
        int tt = ty + s * 8;
        Yt[((size_t)n * TOUT + t0 + tt) * CCH + c0 + tx] = (_Float16)Ls[tx][tt];
    }
}

// ---------------- stage 2: out[(n,t)][d] = sum_c Yt[(n,t)][c] * spT[d][c] ----------------
__global__ __launch_bounds__(256) void gemm2_kernel(const _Float16* __restrict__ Yt,
                                                    const _Float16* __restrict__ spT,
                                                    float* __restrict__ outp) {
    __shared__ __align__(16) _Float16 As[128 * 32];
    __shared__ __align__(16) _Float16 Bs[128 * 32];
    const int tid  = threadIdx.x;
    const int w    = tid >> 6, lane = tid & 63;
    const int quad = lane >> 4, lm = lane & 15;
    const int wm   = w >> 1, wn = w & 1;

    // bijective XCD-chunked remap: 3072 blocks, 384 per XCD
    const int bid = blockIdx.x + blockIdx.y * 3;
    const int lid = (bid & 7) * 384 + (bid >> 3);
    const int n0  = (lid % 3) * 128;
    const int m0  = (lid / 3) * 128;

    f32x4 acc[4][4] = {};

    for (int kt = 0; kt < CCH / 32; ++kt) {
        const int k0 = kt * 32;
#pragma unroll
        for (int ro = 0; ro < 2; ++ro) {
            int gidx = ro * 256 + tid;
            int row  = gidx >> 2;
            int col  = (gidx & 3) * 8;
            gload_lds16(Yt + (size_t)(m0 + row) * CCH + k0 + col,
                        As + (ro * 256 + (tid & ~63)) * 8);
            gload_lds16(spT + (n0 + row) * CCH + k0 + col,
                        Bs + (ro * 256 + (tid & ~63)) * 8);
        }
        __syncthreads();

        f16x8 a[4], b[4];
#pragma unroll
        for (int mi = 0; mi < 4; ++mi)
            a[mi] = *(const f16x8*)(As + (wm * 64 + mi * 16 + lm) * 32 + quad * 8);
#pragma unroll
        for (int ni = 0; ni < 4; ++ni)
            b[ni] = *(const f16x8*)(Bs + (wn * 64 + ni * 16 + lm) * 32 + quad * 8);
#pragma unroll
        for (int mi = 0; mi < 4; ++mi)
#pragma unroll
            for (int ni = 0; ni < 4; ++ni)
                acc[mi][ni] = __builtin_amdgcn_mfma_f32_16x16x32_f16(a[mi], b[ni], acc[mi][ni], 0, 0, 0);
        __syncthreads();
    }

#pragma unroll
    for (int mi = 0; mi < 4; ++mi)
#pragma unroll
        for (int e = 0; e < 4; ++e) {
            int row = m0 + wm * 64 + mi * 16 + quad * 4 + e;
            float* dst = outp + (size_t)row * CCH + n0 + wn * 64 + lm;
#pragma unroll
            for (int ni = 0; ni < 4; ++ni)
                dst[ni * 16] = acc[mi][ni][e];
        }
}

// ---------------- launch ----------------
extern "C" void kernel_launch(void* const* d_in, const int* in_sizes, int n_in,
                              void* d_out, int out_size, void* d_ws, size_t ws_size,
                              hipStream_t stream) {
    const float* noise = (const float*)d_in[0];
    const float* sstd  = (const float*)d_in[1];
    const float* vt    = (const float*)d_in[2];
    const float* kfft  = (const float*)d_in[3];
    float* out = (float*)d_out;

    char* ws = (char*)d_ws;
    // ws layout (16B-aligned):
    float*    h   = (float*)ws;                              // 2048 B
    _Float16* Ht  = (_Float16*)(ws + 2048);                  // 512*416*2  = 425984
    _Float16* spT = (_Float16*)(ws + 428032);                // 384*384*2  = 294912
    _Float16* yb  = (_Float16*)(ws + 722944);                // M1*512*2   = 132120576
    _Float16* Yt  = (_Float16*)(ws + 132843520);             // M2*384*2   = 100663296
    // peak ws usage = 233,506,816 bytes

    build_h_kernel  <<<1, 512, 0, stream>>>(kfft, h);
    build_ht_kernel <<<dim3(512, 2), 256, 0, stream>>>(h, Ht);
    build_spt_kernel<<<CCH, CCH, 0, stream>>>(sstd, vt, spT);

    gemm1_kernel<<<M1 / 128 * (BS / 64), 256, 0, stream>>>(noise, Ht, yb);
    oa_kernel   <<<dim3(TOUT / 32, CCH / 32, 2), 256, 0, stream>>>(yb, Yt);
    gemm2_kernel<<<dim3(CCH / 128, M2 / 128), 256, 0, stream>>>(Yt, spT, out);
}

// Round 4
// 640.059 us; speedup vs baseline: 1.2577x; 1.2577x over previous
//
#include <hip/hip_runtime.h>
#include <hip/hip_bf16.h>

// ---------------- problem constants ----------------
#define TPAD   65656    // t_padded
#define TOUT   65536
#define CCH    384      // channels
#define NROWS  768      // SIZE * C
#define HOP    392
#define NB     168
#define BS     512      // fft block size
#define KPAD   416      // 392 padded to multiple of 32
#define M1     129024   // NROWS * NB
#define M2     131072   // 2 * TOUT
#define NT1    13       // KPAD/32 K-steps in gemm1
#define TAIL   192      // TPAD - (NB-1)*HOP, valid cols of the last block row

typedef __attribute__((ext_vector_type(8))) _Float16 f16x8;
typedef __attribute__((ext_vector_type(4))) _Float16 f16x4;
typedef __attribute__((ext_vector_type(4))) float    f32x4;
typedef __attribute__((ext_vector_type(8))) float    f32x8;

__device__ __forceinline__ void gload_lds16(const void* g, void* l) {
    __builtin_amdgcn_global_load_lds(
        (__attribute__((address_space(1))) void*)g,
        (__attribute__((address_space(3))) void*)l, 16, 0, 0);
}

// ---------------- h = irfft_backward(kernel_fft, 512) ----------------
__global__ void build_h_kernel(const float* __restrict__ kfft, float* __restrict__ h) {
    __shared__ float Ks[257];
    int j = threadIdx.x;          // 0..511
    if (j < 257) Ks[j] = kfft[j];
    __syncthreads();
    float acc = Ks[0] + ((j & 1) ? -Ks[256] : Ks[256]);
    const float w0 = 6.2831853071795864769f / 512.0f;
    for (int f = 1; f < 256; ++f) {
        int m = (f * j) & 511;            // exact integer phase reduction
        acc += 2.0f * Ks[f] * cosf(w0 * (float)m);
    }
    h[j] = acc * (1.0f / 512.0f);
}

// ---------------- Ht[j][i] = h[(j-i) mod 512], i<392 else 0 ----------------
__global__ void build_ht_kernel(const float* __restrict__ h, _Float16* __restrict__ Ht) {
    int j = blockIdx.x;                               // 0..511
    int i = blockIdx.y * 256 + threadIdx.x;           // 0..511
    if (i >= KPAD) return;
    float v = (i < HOP) ? h[(j - i) & 511] : 0.0f;
    Ht[j * KPAD + i] = (_Float16)v;
}

// ---------------- spT[d][c] = std[c] * vt[c][d] ----------------
__global__ void build_spt_kernel(const float* __restrict__ sstd, const float* __restrict__ vt,
                                 _Float16* __restrict__ spT) {
    int d = blockIdx.x;      // 0..383
    int c = threadIdx.x;     // 0..383
    spT[d * CCH + c] = (_Float16)(sstd[c] * vt[c * CCH + d]);
}

// ---------------- fixA[r][i]: zero-padded copy of the b=167 row tails ----------
// fixA[r][i] = noise[r][(NB-1)*HOP + i] for i<192, else 0  (i < KPAD)
__global__ void build_fix_kernel(const float* __restrict__ noise, float* __restrict__ fixA) {
    int r = blockIdx.x;                               // 0..767
    for (int i = threadIdx.x; i < KPAD; i += 256) {
        float v = (i < TAIL) ? noise[(size_t)r * TPAD + (size_t)(NB - 1) * HOP + i] : 0.0f;
        fixA[r * KPAD + i] = v;
    }
}

// ---------------- stage 1: m97 structure, A staged as raw f32 from noise ------
// yb[rb][perm(j)] = sum_i noise16[rb][i] * Ht[j][i]
// Both operands staged via global_load_lds (A: f32 16KB/tile, B: f16 8KB/tile);
// staging never touches registers -> 2-phase TLP hides all latency (round-0's
// proven 122us property). f32->f16 convert happens in the fragment path.
// Rows with b<167: K-pad cols read in-bounds garbage that multiplies Ht=0 -> exact.
// Rows with b==167 redirect to the zero-padded fixA copy (avoids OOB/garbage).
__global__ __launch_bounds__(256) void gemm1_kernel(const float* __restrict__ noise,
                                                    const float* __restrict__ fixA,
                                                    const _Float16* __restrict__ Ht,
                                                    _Float16* __restrict__ yb) {
    __shared__ __align__(16) float    As[128 * 32];   // 16 KB
    __shared__ __align__(16) _Float16 Bs[128 * 32];   // 8 KB
    const int tid  = threadIdx.x;
    const int lane = tid & 63;
    const int w    = tid >> 6;
    const int quad = lane >> 4, lm = lane & 15;
    const int wm   = w >> 1, wn = w & 1;

    // bijective XCD-chunked remap: 4032 blocks, 504 lids per XCD
    const int bid = blockIdx.x + (blockIdx.y << 2);      // hw linear id (x fastest)
    const int lid = (bid & 7) * 504 + (bid >> 3);
    const int n0  = (lid & 3) * 128;
    const int m0  = (lid >> 2) * 128;

    // A staging sources: 4 segs/thread, seg s = ro*256+tid -> row s>>3, f32 col (s&7)*4
    const float* asrc[4];
#pragma unroll
    for (int ro = 0; ro < 4; ++ro) {
        int s   = ro * 256 + tid;
        int row = s >> 3;
        int m   = m0 + row;
        int r   = m / NB, b = m - r * NB;
        const float* base = (b == NB - 1) ? (fixA + (size_t)r * KPAD)
                                          : (noise + (size_t)r * TPAD + b * HOP);
        asrc[ro] = base + (s & 7) * 4;
    }
    // B staging sources: 2 segs/thread, seg s -> row s>>2, f16 col (s&3)*8
    const _Float16* bsrc[2];
#pragma unroll
    for (int ro = 0; ro < 2; ++ro) {
        int s = ro * 256 + tid;
        bsrc[ro] = Ht + (n0 + (s >> 2)) * KPAD + (s & 3) * 8;
    }

    f32x4 acc[4][4] = {};

    for (int kt = 0; kt < NT1; ++kt) {
        const int k0 = kt * 32;
#pragma unroll
        for (int ro = 0; ro < 4; ++ro)
            gload_lds16(asrc[ro] + k0, As + (ro * 256 + (tid & ~63)) * 4);
#pragma unroll
        for (int ro = 0; ro < 2; ++ro)
            gload_lds16(bsrc[ro] + k0, Bs + (ro * 256 + (tid & ~63)) * 8);
        __syncthreads();

        f16x8 a[4], b[4];
#pragma unroll
        for (int mi = 0; mi < 4; ++mi) {
            const float* p = As + (wm * 64 + mi * 16 + lm) * 32 + quad * 8;
            f32x4 v0 = *(const f32x4*)p;
            f32x4 v1 = *(const f32x4*)(p + 4);
            f32x8 v  = {v0.x, v0.y, v0.z, v0.w, v1.x, v1.y, v1.z, v1.w};
            a[mi] = __builtin_convertvector(v, f16x8);
        }
#pragma unroll
        for (int ni = 0; ni < 4; ++ni)
            b[ni] = *(const f16x8*)(Bs + (wn * 64 + ni * 16 + lm) * 32 + quad * 8);
#pragma unroll
        for (int mi = 0; mi < 4; ++mi)
#pragma unroll
            for (int ni = 0; ni < 4; ++ni)
                acc[mi][ni] = __builtin_amdgcn_mfma_f32_16x16x32_f16(a[mi], b[ni], acc[mi][ni], 0, 0, 0);
        __syncthreads();
    }

    // epilogue: lane lm holds logical cols {ni*16+lm}; store contiguously at
    // stored col lm*4+ni -> one 8B f16x4 store per (mi,e); 16 lanes = 128B line.
#pragma unroll
    for (int mi = 0; mi < 4; ++mi)
#pragma unroll
        for (int e = 0; e < 4; ++e) {
            int row = m0 + wm * 64 + mi * 16 + quad * 4 + e;
            f16x4 o = {(_Float16)acc[mi][0][e], (_Float16)acc[mi][1][e],
                       (_Float16)acc[mi][2][e], (_Float16)acc[mi][3][e]};
            *(f16x4*)(yb + (size_t)row * BS + n0 + wn * 64 + lm * 4) = o;
        }
}

// stored col for logical col j (within each 64-col group: lm*4+ni <- ni*16+lm)
__device__ __forceinline__ int permcol(int j) {
    return (j & ~63) | ((j & 15) << 2) | ((j >> 4) & 3);
}

// ---------------- overlap-add + transpose: Yt[n][t][c] ----------------
__global__ __launch_bounds__(256) void oa_kernel(const _Float16* __restrict__ yb,
                                                 _Float16* __restrict__ Yt) {
    __shared__ float Ls[32][33];
    const int tx = threadIdx.x & 31, ty = threadIdx.x >> 5;   // 32 x 8
    const int t0 = blockIdx.x * 32, c0 = blockIdx.y * 32, n = blockIdx.z;
#pragma unroll
    for (int s = 0; s < 4; ++s) {
        int cc = ty + s * 8;
        int r  = n * CCH + c0 + cc;
        int g  = t0 + tx + 120;
        int b  = g / HOP;
        int j  = g - b * HOP;
        size_t base = (size_t)(r * NB + b) * BS;
        float v = (float)yb[base + permcol(j)];
        if (j < 120) v += (float)yb[base - BS + permcol(j + 392)];  // yb[r, b-1, j+392]
        Ls[cc][tx] = v;
    }
    __syncthreads();
#pragma unroll
    for (int s = 0; s < 4; ++s) {
        int tt = ty + s * 8;
        Yt[((size_t)n * TOUT + t0 + tt) * CCH + c0 + tx] = (_Float16)Ls[tx][tt];
    }
}

// ---------------- stage 2: out[(n,t)][d] = sum_c Yt[(n,t)][c] * spT[d][c] ----------------
__global__ __launch_bounds__(256) void gemm2_kernel(const _Float16* __restrict__ Yt,
                                                    const _Float16* __restrict__ spT,
                                                    float* __restrict__ outp) {
    __shared__ __align__(16) _Float16 As[128 * 32];
    __shared__ __align__(16) _Float16 Bs[128 * 32];
    const int tid  = threadIdx.x;
    const int w    = tid >> 6, lane = tid & 63;
    const int quad = lane >> 4, lm = lane & 15;
    const int wm   = w >> 1, wn = w & 1;

    // bijective XCD-chunked remap: 3072 blocks, 384 per XCD
    const int bid = blockIdx.x + blockIdx.y * 3;
    const int lid = (bid & 7) * 384 + (bid >> 3);
    const int n0  = (lid % 3) * 128;
    const int m0  = (lid / 3) * 128;

    f32x4 acc[4][4] = {};

    for (int kt = 0; kt < CCH / 32; ++kt) {
        const int k0 = kt * 32;
#pragma unroll
        for (int ro = 0; ro < 2; ++ro) {
            int gidx = ro * 256 + tid;
            int row  = gidx >> 2;
            int col  = (gidx & 3) * 8;
            gload_lds16(Yt + (size_t)(m0 + row) * CCH + k0 + col,
                        As + (ro * 256 + (tid & ~63)) * 8);
            gload_lds16(spT + (n0 + row) * CCH + k0 + col,
                        Bs + (ro * 256 + (tid & ~63)) * 8);
        }
        __syncthreads();

        f16x8 a[4], b[4];
#pragma unroll
        for (int mi = 0; mi < 4; ++mi)
            a[mi] = *(const f16x8*)(As + (wm * 64 + mi * 16 + lm) * 32 + quad * 8);
#pragma unroll
        for (int ni = 0; ni < 4; ++ni)
            b[ni] = *(const f16x8*)(Bs + (wn * 64 + ni * 16 + lm) * 32 + quad * 8);
#pragma unroll
        for (int mi = 0; mi < 4; ++mi)
#pragma unroll
            for (int ni = 0; ni < 4; ++ni)
                acc[mi][ni] = __builtin_amdgcn_mfma_f32_16x16x32_f16(a[mi], b[ni], acc[mi][ni], 0, 0, 0);
        __syncthreads();
    }

#pragma unroll
    for (int mi = 0; mi < 4; ++mi)
#pragma unroll
        for (int e = 0; e < 4; ++e) {
            int row = m0 + wm * 64 + mi * 16 + quad * 4 + e;
            float* dst = outp + (size_t)row * CCH + n0 + wn * 64 + lm;
#pragma unroll
            for (int ni = 0; ni < 4; ++ni)
                dst[ni * 16] = acc[mi][ni][e];
        }
}

// ---------------- launch ----------------
extern "C" void kernel_launch(void* const* d_in, const int* in_sizes, int n_in,
                              void* d_out, int out_size, void* d_ws, size_t ws_size,
                              hipStream_t stream) {
    const float* noise = (const float*)d_in[0];
    const float* sstd  = (const float*)d_in[1];
    const float* vt    = (const float*)d_in[2];
    const float* kfft  = (const float*)d_in[3];
    float* out = (float*)d_out;

    char* ws = (char*)d_ws;
    // ws layout (16B-aligned):
    float*    h    = (float*)ws;                             // 2048 B
    _Float16* Ht   = (_Float16*)(ws + 2048);                 // 512*416*2  = 425984
    _Float16* spT  = (_Float16*)(ws + 428032);               // 384*384*2  = 294912
    _Float16* yb   = (_Float16*)(ws + 722944);               // M1*512*2   = 132120576
    _Float16* Yt   = (_Float16*)(ws + 132843520);            // M2*384*2   = 100663296
    float*    fixA = (float*)(ws + 233506816);               // 768*416*4  = 1277952
    // peak ws usage = 234,784,768 bytes

    build_h_kernel  <<<1, 512, 0, stream>>>(kfft, h);
    build_ht_kernel <<<dim3(512, 2), 256, 0, stream>>>(h, Ht);
    build_spt_kernel<<<CCH, CCH, 0, stream>>>(sstd, vt, spT);
    build_fix_kernel<<<NROWS, 256, 0, stream>>>(noise, fixA);

    gemm1_kernel<<<dim3(BS / 128, M1 / 128), 256, 0, stream>>>(noise, fixA, Ht, yb);
    oa_kernel   <<<dim3(TOUT / 32, CCH / 32, 2), 256, 0, stream>>>(yb, Yt);
    gemm2_kernel<<<dim3(CCH / 128, M2 / 128), 256, 0, stream>>>(Yt, spT, out);
}